// Round 8
// baseline (166.362 us; speedup 1.0000x reference)
//
#include <hip/hip_runtime.h>
#include <math.h>

// ContactModel R8: one thread per batch, feet processed SEQUENTIALLY to halve
// the live register set, __launch_bounds__(256,8) to pin VGPR<=64 and cross
// the occupancy quantum (waves/CU steps at VGPR=64 per m69: 84 VGPR -> 4
// waves/SIMD; <=64 -> 8). Foot groups computed in reference-shaped direct
// form; all-group via the R7-validated identity T = sum cross(pos,f_m) -
// cop x sum f_m. Force numerics byte-identical to the R1/R6 champion.

__device__ __constant__ float c_local[12][3] = {
    {0.00190115788407966f, -0.01f, -0.00382630379623308f},
    {0.148386399942063f,   -0.01f, -0.028713422052654f},
    {0.133001170607051f,   -0.01f,  0.0516362473449566f},
    {0.0662346661991635f,  -0.01f,  0.0263641606741698f},
    {0.06f,                -0.01f, -0.0187603084619177f},
    {0.045f,               -0.01f,  0.0618569567549652f},
    {0.00190115788407966f, -0.01f,  0.00382630379623308f},
    {0.148386399942063f,   -0.01f,  0.028713422052654f},
    {0.133001170607051f,   -0.01f, -0.0516362473449566f},
    {0.0662346661991635f,  -0.01f, -0.0263641606741698f},
    {0.06f,                -0.01f,  0.0187603084619177f},
    {0.045f,               -0.01f, -0.0618569567549652f}};

__global__ __launch_bounds__(256, 8)
void contact_kernel(const float* __restrict__ joints,
                    const float* __restrict__ jori,
                    float* __restrict__ out, const int B)
{
    const int b = blockIdx.x * blockDim.x + threadIdx.x;
    if (b >= B) return;

    const int bp = (b > 0) ? (b - 1) : b;   // bp==b => vel exactly 0 (ref)
    const float* jr  = joints + (size_t)b  * 72;
    const float* jrp = joints + (size_t)bp * 72;
    const float* mr  = jori   + (size_t)b  * 216;
    const float* mrp = jori   + (size_t)bp * 216;
    const size_t sB = (size_t)B;
    const size_t t3 = (size_t)b * 3;

    // all-group accumulators (live across both feet)
    float aFx=0.f,aFy=0.f,aFz=0.f;     // unmasked force sum
    float aMx=0.f,aMy=0.f,aMz=0.f;     // masked force sum
    float aTx=0.f,aTy=0.f,aTz=0.f;     // sum cross(pos, f_masked)
    float atw=0.f,asx=0.f,asz=0.f;     // cop weights

    const float KF  = 1077.21734501594f;                 // 0.5 * 100000**(2/3)
    const float CFH = (4.0f/3.0f) * KF * sqrtf(0.032f * KF);

    #pragma unroll
    for (int f = 0; f < 2; ++f) {
        float px[6], py[6], pz[6];
        float fx[6], fy[6], fz[6];     // velocity first, then force in-place

        // ---- positions + velocity for this foot's 6 spheres ----
        {
            const int body0 = (f == 0) ? 4 : 9;
            const int sbeg[2] = {0, 4};
            const int scnt[2] = {4, 2};
            #pragma unroll
            for (int bi = 0; bi < 2; ++bi) {
                const int body = body0 + bi;
                const float jx = jr[body*3+0], jy = jr[body*3+1], jz = jr[body*3+2];
                const float* m = mr + body*9;
                const float m00=m[0],m01=m[1],m02=m[2];
                const float m10=m[3],m11=m[4],m12=m[5];
                const float m20=m[6],m21=m[7],m22=m[8];
                const float kx = jrp[body*3+0], ky = jrp[body*3+1], kz = jrp[body*3+2];
                const float* nn = mrp + body*9;
                const float n00=nn[0],n01=nn[1],n02=nn[2];
                const float n10=nn[3],n11=nn[4],n12=nn[5];
                const float n20=nn[6],n21=nn[7],n22=nn[8];
                #pragma unroll
                for (int si = 0; si < 4; ++si) {
                    if (si < scnt[bi]) {
                        const int s  = sbeg[bi] + si;    // local sphere 0..5
                        const int gs = f*6 + s;          // global sphere index
                        const float lx = c_local[gs][0];
                        const float ly = c_local[gs][1];
                        const float lz = c_local[gs][2];
                        const float ax = jx + m00*lx + m01*ly + m02*lz;
                        const float ay = jy + m10*lx + m11*ly + m12*lz;
                        const float az = jz + m20*lx + m21*ly + m22*lz;
                        const float bx = kx + n00*lx + n01*ly + n02*lz;
                        const float by = ky + n10*lx + n11*ly + n12*lz;
                        const float bz = kz + n20*lx + n21*ly + n22*lz;
                        px[s] = ax; py[s] = ay; pz[s] = az;
                        fx[s] = (ax - bx) * 20.0f;   // 1/DT = 20
                        fy[s] = (ay - by) * 20.0f;
                        fz[s] = (az - bz) * 20.0f;
                    }
                }
            }
        }

        // ---- contact forces (R1 numerics, in-place over velocity) ----
        #pragma unroll
        for (int s = 0; s < 6; ++s) {
            const float vx = fx[s], vy = fy[s], vz = fz[s];
            const float ind     = -py[s];                    // GROUND_HEIGHT = 0
            const float ind_vel = -vy;
            const float q   = ind*ind + 1e-5f;
            const float fH  = CFH * sqrtf(q * sqrtf(q));     // q^0.75
            const float fHd = fH * (1.0f + 0.3f * ind_vel);  // 1.5*DISSIPATION
            const float t1 = (0.5f*tanhf(50.0f*(ind_vel + 3.3333333333333335f)) + 0.5f) + 1e-16f;
            const float t2 = (0.5f*tanhf(300.0f*ind) + 0.5f) + 1e-16f;
            const float fn = t1 * t2 * fHd;
            const float vslip = sqrtf(vx*vx + vz*vz + 1e-5f);
            const float vrel  = vslip * 5.0f;                // / TRANSITION_VEL
            // STATIC==DYNAMIC==0.8 -> 2*(S-D)/(1+vrel^2) term is exactly 0
            const float mu  = fminf(vrel, 1.0f) * 0.8f + 0.5f * vslip;
            const float ffr = fn * mu;
            const float sc  = ffr / (vslip + 1e-5f);
            fx[s] = -sc * vx;
            fy[s] = fn;
            fz[s] = -sc * vz;
        }

        // ---- per-foot sums ----
        float SFx=0.f,SFy=0.f,SFz=0.f;
        float SMx=0.f,SMy=0.f,SMz=0.f;
        float T0x=0.f,T0y=0.f,T0z=0.f;
        float tw=0.f, sx=0.f, sz=0.f;
        #pragma unroll
        for (int s = 0; s < 6; ++s) {
            SFx += fx[s]; SFy += fy[s]; SFz += fz[s];
            if (fy[s] > 0.f) {
                tw += fy[s]; sx += px[s]*fy[s]; sz += pz[s]*fy[s];
                SMx += fx[s]; SMy += fy[s]; SMz += fz[s];
                T0x += py[s]*fz[s] - pz[s]*fy[s];
                T0y += pz[s]*fx[s] - px[s]*fz[s];
                T0z += px[s]*fy[s] - py[s]*fx[s];
            }
        }

        // ---- foot-group outputs (reference-shaped direct form) ----
        const bool  hasf = tw > 0.f;
        const float cxf  = hasf ? sx / tw : 0.f;
        const float czf  = hasf ? sz / tw : 0.f;
        float Txf=0.f, Tyf=0.f, Tzf=0.f;
        #pragma unroll
        for (int s = 0; s < 6; ++s) {
            if (fy[s] > 0.f) {
                const float rx = px[s]-cxf, ry = py[s], rz = pz[s]-czf; // cy==0
                Txf += ry*fz[s] - rz*fy[s];
                Tyf += rz*fx[s] - rx*fz[s];
                Tzf += rx*fy[s] - ry*fx[s];
            }
        }

        // ---- foot stores ----
        // layout (floats): force 0 | torque 3B | cop 6B | sf 9B | pos 45B
        //   | f_r 81B | f_l 84B | t_r 87B | t_l 90B | c_r 93B | c_l 96B
        float* o;
        o = out + sB*(81 + f*3);  o[t3]=SFx; o[t3+1]=SFy; o[t3+2]=SFz;
        o = out + sB*(87 + f*3);  o[t3]=Txf; o[t3+1]=Tyf; o[t3+2]=Tzf;
        o = out + sB*(93 + f*3);  o[t3]=cxf; o[t3+1]=0.f; o[t3+2]=czf;

        float* osf = out + sB*9  + (size_t)b*36 + f*18;
        float* opp = out + sB*45 + (size_t)b*36 + f*18;
        if ((B & 3) == 0) {
            // bases 16B-aligned + b*144; f*72 -> f=0 16B-aligned, f=1 8-aligned
            float bufF[18], bufP[18];
            #pragma unroll
            for (int s = 0; s < 6; ++s) {
                bufF[s*3+0]=fx[s]; bufF[s*3+1]=fy[s]; bufF[s*3+2]=fz[s];
                bufP[s*3+0]=px[s]; bufP[s*3+1]=py[s]; bufP[s*3+2]=pz[s];
            }
            if (f == 0) {
                #pragma unroll
                for (int i = 0; i < 4; ++i) {
                    reinterpret_cast<float4*>(osf)[i] =
                        make_float4(bufF[i*4], bufF[i*4+1], bufF[i*4+2], bufF[i*4+3]);
                    reinterpret_cast<float4*>(opp)[i] =
                        make_float4(bufP[i*4], bufP[i*4+1], bufP[i*4+2], bufP[i*4+3]);
                }
                reinterpret_cast<float2*>(osf)[8] = make_float2(bufF[16], bufF[17]);
                reinterpret_cast<float2*>(opp)[8] = make_float2(bufP[16], bufP[17]);
            } else {
                reinterpret_cast<float2*>(osf)[0] = make_float2(bufF[0], bufF[1]);
                reinterpret_cast<float2*>(opp)[0] = make_float2(bufP[0], bufP[1]);
                #pragma unroll
                for (int i = 0; i < 4; ++i) {
                    reinterpret_cast<float4*>(osf + 2)[i] =
                        make_float4(bufF[2+i*4], bufF[3+i*4], bufF[4+i*4], bufF[5+i*4]);
                    reinterpret_cast<float4*>(opp + 2)[i] =
                        make_float4(bufP[2+i*4], bufP[3+i*4], bufP[4+i*4], bufP[5+i*4]);
                }
            }
        } else {
            #pragma unroll
            for (int s = 0; s < 6; ++s) {
                osf[s*3+0]=fx[s]; osf[s*3+1]=fy[s]; osf[s*3+2]=fz[s];
                opp[s*3+0]=px[s]; opp[s*3+1]=py[s]; opp[s*3+2]=pz[s];
            }
        }

        // ---- accumulate all-group ----
        aFx += SFx; aFy += SFy; aFz += SFz;
        aMx += SMx; aMy += SMy; aMz += SMz;
        aTx += T0x; aTy += T0y; aTz += T0z;
        atw += tw;  asx += sx;  asz += sz;
    }

    // ---- all-group outputs (R7-validated identity) ----
    const bool  hasa = atw > 0.f;
    const float cxa  = hasa ? asx / atw : 0.f;
    const float cza  = hasa ? asz / atw : 0.f;
    const float Txa = aTx + cza*aMy;
    const float Tya = aTy - cza*aMx + cxa*aMz;
    const float Tza = aTz - cxa*aMy;

    float* o;
    o = out;          o[t3]=aFx; o[t3+1]=aFy; o[t3+2]=aFz;
    o = out + sB*3;   o[t3]=Txa; o[t3+1]=Tya; o[t3+2]=Tza;
    o = out + sB*6;   o[t3]=cxa; o[t3+1]=0.f; o[t3+2]=cza;
}

extern "C" void kernel_launch(void* const* d_in, const int* in_sizes, int n_in,
                              void* d_out, int out_size, void* d_ws, size_t ws_size,
                              hipStream_t stream) {
    const float* joints = (const float*)d_in[0];
    const float* jori   = (const float*)d_in[1];
    float* out = (float*)d_out;
    const int B = in_sizes[0] / 72;   // joints is (B, 24, 3)
    const int block = 256;
    const int grid  = (B + block - 1) / block;
    contact_kernel<<<grid, block, 0, stream>>>(joints, jori, out, B);
}

// Round 9
// 95.235 us; speedup vs baseline: 1.7469x; 1.7469x over previous
//
#include <hip/hip_runtime.h>
#include <math.h>

// ContactModel R9: R8's sequential-feet structure with the waves-per-EU cap
// REMOVED (plain __launch_bounds__(256)). R8's (256,8) forced VGPR=32 ->
// massive scratch spills (WRITE 285MB vs 117MB true). The structure's live
// set (~36 sphere floats + 12 all-group accumulators) should naturally land
// near 56-72 VGPR; if <=64 we get 8 waves/SIMD (vs champion's 6 at 84 VGPR)
// with no spill risk. Numerics byte-identical to R8 (passed, absmax 524288).

__device__ __constant__ float c_local[12][3] = {
    {0.00190115788407966f, -0.01f, -0.00382630379623308f},
    {0.148386399942063f,   -0.01f, -0.028713422052654f},
    {0.133001170607051f,   -0.01f,  0.0516362473449566f},
    {0.0662346661991635f,  -0.01f,  0.0263641606741698f},
    {0.06f,                -0.01f, -0.0187603084619177f},
    {0.045f,               -0.01f,  0.0618569567549652f},
    {0.00190115788407966f, -0.01f,  0.00382630379623308f},
    {0.148386399942063f,   -0.01f,  0.028713422052654f},
    {0.133001170607051f,   -0.01f, -0.0516362473449566f},
    {0.0662346661991635f,  -0.01f, -0.0263641606741698f},
    {0.06f,                -0.01f,  0.0187603084619177f},
    {0.045f,               -0.01f, -0.0618569567549652f}};

__global__ __launch_bounds__(256)
void contact_kernel(const float* __restrict__ joints,
                    const float* __restrict__ jori,
                    float* __restrict__ out, const int B)
{
    const int b = blockIdx.x * blockDim.x + threadIdx.x;
    if (b >= B) return;

    const int bp = (b > 0) ? (b - 1) : b;   // bp==b => vel exactly 0 (ref)
    const float* jr  = joints + (size_t)b  * 72;
    const float* jrp = joints + (size_t)bp * 72;
    const float* mr  = jori   + (size_t)b  * 216;
    const float* mrp = jori   + (size_t)bp * 216;
    const size_t sB = (size_t)B;
    const size_t t3 = (size_t)b * 3;

    // all-group accumulators (live across both feet)
    float aFx=0.f,aFy=0.f,aFz=0.f;     // unmasked force sum
    float aMx=0.f,aMy=0.f,aMz=0.f;     // masked force sum
    float aTx=0.f,aTy=0.f,aTz=0.f;     // sum cross(pos, f_masked)
    float atw=0.f,asx=0.f,asz=0.f;     // cop weights

    const float KF  = 1077.21734501594f;                 // 0.5 * 100000**(2/3)
    const float CFH = (4.0f/3.0f) * KF * sqrtf(0.032f * KF);

    #pragma unroll
    for (int f = 0; f < 2; ++f) {
        float px[6], py[6], pz[6];
        float fx[6], fy[6], fz[6];     // velocity first, then force in-place

        // ---- positions + velocity for this foot's 6 spheres ----
        {
            const int body0 = (f == 0) ? 4 : 9;
            const int sbeg[2] = {0, 4};
            const int scnt[2] = {4, 2};
            #pragma unroll
            for (int bi = 0; bi < 2; ++bi) {
                const int body = body0 + bi;
                const float jx = jr[body*3+0], jy = jr[body*3+1], jz = jr[body*3+2];
                const float* m = mr + body*9;
                const float m00=m[0],m01=m[1],m02=m[2];
                const float m10=m[3],m11=m[4],m12=m[5];
                const float m20=m[6],m21=m[7],m22=m[8];
                const float kx = jrp[body*3+0], ky = jrp[body*3+1], kz = jrp[body*3+2];
                const float* nn = mrp + body*9;
                const float n00=nn[0],n01=nn[1],n02=nn[2];
                const float n10=nn[3],n11=nn[4],n12=nn[5];
                const float n20=nn[6],n21=nn[7],n22=nn[8];
                #pragma unroll
                for (int si = 0; si < 4; ++si) {
                    if (si < scnt[bi]) {
                        const int s  = sbeg[bi] + si;    // local sphere 0..5
                        const int gs = f*6 + s;          // global sphere index
                        const float lx = c_local[gs][0];
                        const float ly = c_local[gs][1];
                        const float lz = c_local[gs][2];
                        const float ax = jx + m00*lx + m01*ly + m02*lz;
                        const float ay = jy + m10*lx + m11*ly + m12*lz;
                        const float az = jz + m20*lx + m21*ly + m22*lz;
                        const float bx = kx + n00*lx + n01*ly + n02*lz;
                        const float by = ky + n10*lx + n11*ly + n12*lz;
                        const float bz = kz + n20*lx + n21*ly + n22*lz;
                        px[s] = ax; py[s] = ay; pz[s] = az;
                        fx[s] = (ax - bx) * 20.0f;   // 1/DT = 20
                        fy[s] = (ay - by) * 20.0f;
                        fz[s] = (az - bz) * 20.0f;
                    }
                }
            }
        }

        // ---- contact forces (R1 numerics, in-place over velocity) ----
        #pragma unroll
        for (int s = 0; s < 6; ++s) {
            const float vx = fx[s], vy = fy[s], vz = fz[s];
            const float ind     = -py[s];                    // GROUND_HEIGHT = 0
            const float ind_vel = -vy;
            const float q   = ind*ind + 1e-5f;
            const float fH  = CFH * sqrtf(q * sqrtf(q));     // q^0.75
            const float fHd = fH * (1.0f + 0.3f * ind_vel);  // 1.5*DISSIPATION
            const float t1 = (0.5f*tanhf(50.0f*(ind_vel + 3.3333333333333335f)) + 0.5f) + 1e-16f;
            const float t2 = (0.5f*tanhf(300.0f*ind) + 0.5f) + 1e-16f;
            const float fn = t1 * t2 * fHd;
            const float vslip = sqrtf(vx*vx + vz*vz + 1e-5f);
            const float vrel  = vslip * 5.0f;                // / TRANSITION_VEL
            // STATIC==DYNAMIC==0.8 -> 2*(S-D)/(1+vrel^2) term is exactly 0
            const float mu  = fminf(vrel, 1.0f) * 0.8f + 0.5f * vslip;
            const float ffr = fn * mu;
            const float sc  = ffr / (vslip + 1e-5f);
            fx[s] = -sc * vx;
            fy[s] = fn;
            fz[s] = -sc * vz;
        }

        // ---- per-foot sums ----
        float SFx=0.f,SFy=0.f,SFz=0.f;
        float SMx=0.f,SMy=0.f,SMz=0.f;
        float T0x=0.f,T0y=0.f,T0z=0.f;
        float tw=0.f, sx=0.f, sz=0.f;
        #pragma unroll
        for (int s = 0; s < 6; ++s) {
            SFx += fx[s]; SFy += fy[s]; SFz += fz[s];
            if (fy[s] > 0.f) {
                tw += fy[s]; sx += px[s]*fy[s]; sz += pz[s]*fy[s];
                SMx += fx[s]; SMy += fy[s]; SMz += fz[s];
                T0x += py[s]*fz[s] - pz[s]*fy[s];
                T0y += pz[s]*fx[s] - px[s]*fz[s];
                T0z += px[s]*fy[s] - py[s]*fx[s];
            }
        }

        // ---- foot-group outputs (reference-shaped direct form) ----
        const bool  hasf = tw > 0.f;
        const float cxf  = hasf ? sx / tw : 0.f;
        const float czf  = hasf ? sz / tw : 0.f;
        float Txf=0.f, Tyf=0.f, Tzf=0.f;
        #pragma unroll
        for (int s = 0; s < 6; ++s) {
            if (fy[s] > 0.f) {
                const float rx = px[s]-cxf, ry = py[s], rz = pz[s]-czf; // cy==0
                Txf += ry*fz[s] - rz*fy[s];
                Tyf += rz*fx[s] - rx*fz[s];
                Tzf += rx*fy[s] - ry*fx[s];
            }
        }

        // ---- foot stores ----
        // layout (floats): force 0 | torque 3B | cop 6B | sf 9B | pos 45B
        //   | f_r 81B | f_l 84B | t_r 87B | t_l 90B | c_r 93B | c_l 96B
        float* o;
        o = out + sB*(81 + f*3);  o[t3]=SFx; o[t3+1]=SFy; o[t3+2]=SFz;
        o = out + sB*(87 + f*3);  o[t3]=Txf; o[t3+1]=Tyf; o[t3+2]=Tzf;
        o = out + sB*(93 + f*3);  o[t3]=cxf; o[t3+1]=0.f; o[t3+2]=czf;

        float* osf = out + sB*9  + (size_t)b*36 + f*18;
        float* opp = out + sB*45 + (size_t)b*36 + f*18;
        if ((B & 3) == 0) {
            // bases 16B-aligned + b*144; f*72 -> f=0 16B-aligned, f=1 8-aligned
            float bufF[18], bufP[18];
            #pragma unroll
            for (int s = 0; s < 6; ++s) {
                bufF[s*3+0]=fx[s]; bufF[s*3+1]=fy[s]; bufF[s*3+2]=fz[s];
                bufP[s*3+0]=px[s]; bufP[s*3+1]=py[s]; bufP[s*3+2]=pz[s];
            }
            if (f == 0) {
                #pragma unroll
                for (int i = 0; i < 4; ++i) {
                    reinterpret_cast<float4*>(osf)[i] =
                        make_float4(bufF[i*4], bufF[i*4+1], bufF[i*4+2], bufF[i*4+3]);
                    reinterpret_cast<float4*>(opp)[i] =
                        make_float4(bufP[i*4], bufP[i*4+1], bufP[i*4+2], bufP[i*4+3]);
                }
                reinterpret_cast<float2*>(osf)[8] = make_float2(bufF[16], bufF[17]);
                reinterpret_cast<float2*>(opp)[8] = make_float2(bufP[16], bufP[17]);
            } else {
                reinterpret_cast<float2*>(osf)[0] = make_float2(bufF[0], bufF[1]);
                reinterpret_cast<float2*>(opp)[0] = make_float2(bufP[0], bufP[1]);
                #pragma unroll
                for (int i = 0; i < 4; ++i) {
                    reinterpret_cast<float4*>(osf + 2)[i] =
                        make_float4(bufF[2+i*4], bufF[3+i*4], bufF[4+i*4], bufF[5+i*4]);
                    reinterpret_cast<float4*>(opp + 2)[i] =
                        make_float4(bufP[2+i*4], bufP[3+i*4], bufP[4+i*4], bufP[5+i*4]);
                }
            }
        } else {
            #pragma unroll
            for (int s = 0; s < 6; ++s) {
                osf[s*3+0]=fx[s]; osf[s*3+1]=fy[s]; osf[s*3+2]=fz[s];
                opp[s*3+0]=px[s]; opp[s*3+1]=py[s]; opp[s*3+2]=pz[s];
            }
        }

        // ---- accumulate all-group ----
        aFx += SFx; aFy += SFy; aFz += SFz;
        aMx += SMx; aMy += SMy; aMz += SMz;
        aTx += T0x; aTy += T0y; aTz += T0z;
        atw += tw;  asx += sx;  asz += sz;
    }

    // ---- all-group outputs (R7-validated identity) ----
    const bool  hasa = atw > 0.f;
    const float cxa  = hasa ? asx / atw : 0.f;
    const float cza  = hasa ? asz / atw : 0.f;
    const float Txa = aTx + cza*aMy;
    const float Tya = aTy - cza*aMx + cxa*aMz;
    const float Tza = aTz - cxa*aMy;

    float* o;
    o = out;          o[t3]=aFx; o[t3+1]=aFy; o[t3+2]=aFz;
    o = out + sB*3;   o[t3]=Txa; o[t3+1]=Tya; o[t3+2]=Tza;
    o = out + sB*6;   o[t3]=cxa; o[t3+1]=0.f; o[t3+2]=cza;
}

extern "C" void kernel_launch(void* const* d_in, const int* in_sizes, int n_in,
                              void* d_out, int out_size, void* d_ws, size_t ws_size,
                              hipStream_t stream) {
    const float* joints = (const float*)d_in[0];
    const float* jori   = (const float*)d_in[1];
    float* out = (float*)d_out;
    const int B = in_sizes[0] / 72;   // joints is (B, 24, 3)
    const int block = 256;
    const int grid  = (B + block - 1) / block;
    contact_kernel<<<grid, block, 0, stream>>>(joints, jori, out, B);
}

// Round 10
// 67.135 us; speedup vs baseline: 2.4780x; 1.4186x over previous
//
#include <hip/hip_runtime.h>
#include <math.h>

// ContactModel R10: champion structure + EXPLICIT full load hoist.
// Work-limited grid (1024 blocks = 4/CU = 16 waves/CU) + latency-bound =>
// the lever is loads-in-flight per thread. All 96 input floats (own + prev
// row, bodies 4,5,9,10) are loaded into registers BEFORE any force math, so
// every VMEM op issues before the first dependent use (libm tanh's branchy
// expansion otherwise acts as a scheduling fence). Force/reduction/store
// code byte-identical to the R1/R6 champion (67.2 us, absmax 524288).

__device__ __constant__ float c_local[12][3] = {
    {0.00190115788407966f, -0.01f, -0.00382630379623308f},
    {0.148386399942063f,   -0.01f, -0.028713422052654f},
    {0.133001170607051f,   -0.01f,  0.0516362473449566f},
    {0.0662346661991635f,  -0.01f,  0.0263641606741698f},
    {0.06f,                -0.01f, -0.0187603084619177f},
    {0.045f,               -0.01f,  0.0618569567549652f},
    {0.00190115788407966f, -0.01f,  0.00382630379623308f},
    {0.148386399942063f,   -0.01f,  0.028713422052654f},
    {0.133001170607051f,   -0.01f, -0.0516362473449566f},
    {0.0662346661991635f,  -0.01f, -0.0263641606741698f},
    {0.06f,                -0.01f,  0.0187603084619177f},
    {0.045f,               -0.01f, -0.0618569567549652f}};

__global__ __launch_bounds__(256)
void contact_kernel(const float* __restrict__ joints,
                    const float* __restrict__ jori,
                    float* __restrict__ out, const int B)
{
    const int b = blockIdx.x * blockDim.x + threadIdx.x;
    if (b >= B) return;

    const int bp = (b > 0) ? (b - 1) : b;   // bp==b => vel exactly 0 (ref)
    const float* jr  = joints + (size_t)b  * 72;
    const float* jrp = joints + (size_t)bp * 72;
    const float* mr  = jori   + (size_t)b  * 216;
    const float* mrp = jori   + (size_t)bp * 216;

    // ---- PHASE 1: hoist ALL loads (96 floats) into registers ----
    float J[12], P[12];     // jpos own/prev: bodies {4,5,9,10} x 3
    float M[36], N[36];     // ori  own/prev: bodies {4,5,9,10} x 9
    {
        const int bodies[4] = {4, 5, 9, 10};
        #pragma unroll
        for (int bi = 0; bi < 4; ++bi) {
            const int body = bodies[bi];
            #pragma unroll
            for (int c = 0; c < 3; ++c) {
                J[bi*3+c] = jr [body*3+c];
                P[bi*3+c] = jrp[body*3+c];
            }
            #pragma unroll
            for (int c = 0; c < 9; ++c) {
                M[bi*9+c] = mr [body*9+c];
                N[bi*9+c] = mrp[body*9+c];
            }
        }
    }

    // ---- PHASE 2: positions + velocity (pure FMA, consumes M/N/J/P) ----
    float px[12], py[12], pz[12];
    float fx[12], fy[12], fz[12];   // velocity first, then force in-place
    {
        const int sbeg[4] = {0, 4, 6, 10};
        const int scnt[4] = {4, 2, 4, 2};
        #pragma unroll
        for (int bi = 0; bi < 4; ++bi) {
            const float jx = J[bi*3+0], jy = J[bi*3+1], jz = J[bi*3+2];
            const float kx = P[bi*3+0], ky = P[bi*3+1], kz = P[bi*3+2];
            const float m00=M[bi*9+0],m01=M[bi*9+1],m02=M[bi*9+2];
            const float m10=M[bi*9+3],m11=M[bi*9+4],m12=M[bi*9+5];
            const float m20=M[bi*9+6],m21=M[bi*9+7],m22=M[bi*9+8];
            const float n00=N[bi*9+0],n01=N[bi*9+1],n02=N[bi*9+2];
            const float n10=N[bi*9+3],n11=N[bi*9+4],n12=N[bi*9+5];
            const float n20=N[bi*9+6],n21=N[bi*9+7],n22=N[bi*9+8];
            #pragma unroll
            for (int si = 0; si < 4; ++si) {
                if (si < scnt[bi]) {
                    const int s = sbeg[bi] + si;
                    const float lx = c_local[s][0];
                    const float ly = c_local[s][1];
                    const float lz = c_local[s][2];
                    const float ax = jx + m00*lx + m01*ly + m02*lz;
                    const float ay = jy + m10*lx + m11*ly + m12*lz;
                    const float az = jz + m20*lx + m21*ly + m22*lz;
                    const float bx = kx + n00*lx + n01*ly + n02*lz;
                    const float by = ky + n10*lx + n11*ly + n12*lz;
                    const float bz = kz + n20*lx + n21*ly + n22*lz;
                    px[s] = ax; py[s] = ay; pz[s] = az;
                    fx[s] = (ax - bx) * 20.0f;   // 1/DT = 20
                    fy[s] = (ay - by) * 20.0f;
                    fz[s] = (az - bz) * 20.0f;
                }
            }
        }
    }

    // ---- PHASE 3: contact forces (champion numerics, in-place) ----
    const float KF  = 1077.21734501594f;                 // 0.5 * 100000**(2/3)
    const float CFH = (4.0f/3.0f) * KF * sqrtf(0.032f * KF);
    #pragma unroll
    for (int s = 0; s < 12; ++s) {
        const float vx = fx[s], vy = fy[s], vz = fz[s];
        const float ind     = -py[s];                    // GROUND_HEIGHT = 0
        const float ind_vel = -vy;
        const float q   = ind*ind + 1e-5f;
        const float fH  = CFH * sqrtf(q * sqrtf(q));     // q^0.75
        const float fHd = fH * (1.0f + 0.3f * ind_vel);  // 1.5*DISSIPATION = 0.3
        const float t1 = (0.5f*tanhf(50.0f*(ind_vel + 3.3333333333333335f)) + 0.5f) + 1e-16f;
        const float t2 = (0.5f*tanhf(300.0f*ind) + 0.5f) + 1e-16f;
        const float fn = t1 * t2 * fHd;
        const float vslip = sqrtf(vx*vx + vz*vz + 1e-5f);
        const float vrel  = vslip * 5.0f;                // / TRANSITION_VELOCITY
        // STATIC==DYNAMIC==0.8 -> 2*(S-D)/(1+vrel^2) term is exactly 0
        const float mu  = fminf(vrel, 1.0f) * 0.8f + 0.5f * vslip;
        const float ffr = fn * mu;
        const float sc  = ffr / (vslip + 1e-5f);
        fx[s] = -sc * vx;
        fy[s] = fn;
        fz[s] = -sc * vz;
    }

    // ---- group reductions: g=0 all, g=1 right(0..6), g=2 left(6..12) ----
    float res[3][9];
    const int gs0[3] = {0, 0, 6};
    const int gs1[3] = {12, 6, 12};
    #pragma unroll
    for (int g = 0; g < 3; ++g) {
        float Fx=0.f, Fy=0.f, Fz=0.f, tw=0.f, sx=0.f, sz=0.f;
        #pragma unroll
        for (int s = 0; s < 12; ++s) {
            if (s >= gs0[g] && s < gs1[g]) {
                Fx += fx[s]; Fy += fy[s]; Fz += fz[s];
                const float w = fy[s] > 0.f ? fy[s] : 0.f;
                tw += w;
                sx += px[s] * w;
                sz += pz[s] * w;
            }
        }
        const bool has = tw > 0.f;
        const float cx = has ? sx / tw : 0.f;
        const float cz = has ? sz / tw : 0.f;
        float Tx=0.f, Ty=0.f, Tz=0.f;
        #pragma unroll
        for (int s = 0; s < 12; ++s) {
            if (s >= gs0[g] && s < gs1[g]) {
                if (fy[s] > 0.f) {
                    const float rx = px[s]-cx, ry = py[s], rz = pz[s]-cz;  // cy==0
                    Tx += ry*fz[s] - rz*fy[s];
                    Ty += rz*fx[s] - rx*fz[s];
                    Tz += rx*fy[s] - ry*fx[s];
                }
            }
        }
        res[g][0]=Fx; res[g][1]=Fy; res[g][2]=Fz;
        res[g][3]=Tx; res[g][4]=Ty; res[g][5]=Tz;
        res[g][6]=cx; res[g][7]=0.f; res[g][8]=cz;
    }

    // ---- stores (champion layout) ----
    const size_t sB = (size_t)B;
    const size_t t3 = (size_t)b * 3;
    float* o;
    o = out;           o[t3]=res[0][0]; o[t3+1]=res[0][1]; o[t3+2]=res[0][2];
    o = out + sB*3;    o[t3]=res[0][3]; o[t3+1]=res[0][4]; o[t3+2]=res[0][5];
    o = out + sB*6;    o[t3]=res[0][6]; o[t3+1]=res[0][7]; o[t3+2]=res[0][8];
    o = out + sB*81;   o[t3]=res[1][0]; o[t3+1]=res[1][1]; o[t3+2]=res[1][2];
    o = out + sB*84;   o[t3]=res[2][0]; o[t3+1]=res[2][1]; o[t3+2]=res[2][2];
    o = out + sB*87;   o[t3]=res[1][3]; o[t3+1]=res[1][4]; o[t3+2]=res[1][5];
    o = out + sB*90;   o[t3]=res[2][3]; o[t3+1]=res[2][4]; o[t3+2]=res[2][5];
    o = out + sB*93;   o[t3]=res[1][6]; o[t3+1]=res[1][7]; o[t3+2]=res[1][8];
    o = out + sB*96;   o[t3]=res[2][6]; o[t3+1]=res[2][7]; o[t3+2]=res[2][8];

    float* osf = out + sB*9  + (size_t)b*36;
    float* opp = out + sB*45 + (size_t)b*36;
    if ((B & 3) == 0) {  // 16B alignment guaranteed
        float bufF[36], bufP[36];
        #pragma unroll
        for (int s = 0; s < 12; ++s) {
            bufF[s*3+0]=fx[s]; bufF[s*3+1]=fy[s]; bufF[s*3+2]=fz[s];
            bufP[s*3+0]=px[s]; bufP[s*3+1]=py[s]; bufP[s*3+2]=pz[s];
        }
        #pragma unroll
        for (int i = 0; i < 9; ++i) {
            reinterpret_cast<float4*>(osf)[i] = reinterpret_cast<float4*>(bufF)[i];
            reinterpret_cast<float4*>(opp)[i] = reinterpret_cast<float4*>(bufP)[i];
        }
    } else {
        #pragma unroll
        for (int s = 0; s < 12; ++s) {
            osf[s*3+0]=fx[s]; osf[s*3+1]=fy[s]; osf[s*3+2]=fz[s];
            opp[s*3+0]=px[s]; opp[s*3+1]=py[s]; opp[s*3+2]=pz[s];
        }
    }
}

extern "C" void kernel_launch(void* const* d_in, const int* in_sizes, int n_in,
                              void* d_out, int out_size, void* d_ws, size_t ws_size,
                              hipStream_t stream) {
    const float* joints = (const float*)d_in[0];
    const float* jori   = (const float*)d_in[1];
    float* out = (float*)d_out;
    const int B = in_sizes[0] / 72;   // joints is (B, 24, 3)
    const int block = 256;
    const int grid  = (B + block - 1) / block;
    contact_kernel<<<grid, block, 0, stream>>>(joints, jori, out, B);
}